// Round 13
// baseline (320.836 us; speedup 1.0000x reference)
//
#include <hip/hip_runtime.h>

#define F_IN 512
#define H1   8
#define D1   8
#define C1   64   // H1*D1
#define C2   40
#define C2P  48   // padded cols for MFMA gemm2

#define BKT_SH   7
#define BKT_W    128
#define NBKT_MAX 1024
#define NBLK     128

using short8 = __attribute__((ext_vector_type(8))) short;
using f32x4  = __attribute__((ext_vector_type(4))) float;
using bf8v   = __attribute__((ext_vector_type(8))) __bf16;

__device__ __forceinline__ float leaky02(float x) { return x > 0.f ? x : 0.2f * x; }
__device__ __forceinline__ float bf2f(unsigned short u) {
    return __builtin_bit_cast(float, ((unsigned)u) << 16);
}
__device__ __forceinline__ unsigned short f2bf(float v) {
    return __builtin_bit_cast(unsigned short, (__bf16)v);
}
__device__ __forceinline__ short8 cvt_bf16x8(float4 a, float4 b) {
    bf8v r;
    r[0] = (__bf16)a.x; r[1] = (__bf16)a.y; r[2] = (__bf16)a.z; r[3] = (__bf16)a.w;
    r[4] = (__bf16)b.x; r[5] = (__bf16)b.y; r[6] = (__bf16)b.z; r[7] = (__bf16)b.w;
    return __builtin_bit_cast(short8, r);
}

// ---------------------------------------------------------------------------
// One-time weight transpose+cast: Bt1 (64x512), Bt2 (48x64, cols>=40 zero).
// ---------------------------------------------------------------------------
__global__ __launch_bounds__(256) void wconv_kernel(
    const float* __restrict__ W1, const float* __restrict__ W2,
    unsigned short* __restrict__ Bt1, unsigned short* __restrict__ Bt2)
{
    int idx = blockIdx.x * 256 + threadIdx.x;
    if (idx < F_IN * C1) {
        int k = idx >> 6, c = idx & 63;
        Bt1[(size_t)c * F_IN + k] = f2bf(W1[idx]);
    } else if (idx < F_IN * C1 + C2P * 64) {
        int j = idx - F_IN * C1;
        int c = j >> 6, k = j & 63;
        float v = (c < C2) ? W2[k * C2 + c] : 0.f;
        Bt2[c * 64 + k] = f2bf(v);
    }
}

// ---------------------------------------------------------------------------
// GEMM1 body (MFMA bf16, fused alpha1) — shared by the three fused launches.
// ---------------------------------------------------------------------------
__device__ __forceinline__ void gemm1_body(
    int gblk, int tid,
    const float* __restrict__ x, const unsigned short* __restrict__ Bt1,
    const float* __restrict__ a_src, const float* __restrict__ a_dst,
    unsigned short* __restrict__ h1b, float* __restrict__ as1,
    float* __restrict__ ad1, int N)
{
    const int w    = tid >> 6;
    const int lane = tid & 63;
    const int lo   = lane & 15;
    const int kg   = lane >> 4;
    const int n0   = gblk * 128 + w * 32;

    const int nA = min(n0 + lo, N - 1);
    const int nB = min(n0 + 16 + lo, N - 1);
    const float* xA = x + (size_t)nA * F_IN + kg * 8;
    const float* xB = x + (size_t)nB * F_IN + kg * 8;
    const unsigned short* bp = Bt1 + (size_t)lo * F_IN + kg * 8;

    float a_s[4], a_d[4];
    #pragma unroll
    for (int nt = 0; nt < 4; ++nt) {
        a_s[nt] = a_src[nt * 16 + lo];
        a_d[nt] = a_dst[nt * 16 + lo];
    }

    f32x4 acc[2][4];
    #pragma unroll
    for (int mt = 0; mt < 2; ++mt)
        #pragma unroll
        for (int nt = 0; nt < 4; ++nt)
            acc[mt][nt] = (f32x4){0.f, 0.f, 0.f, 0.f};

    #pragma unroll 4
    for (int s = 0; s < 16; ++s) {
        const int kb = s * 32;
        float4 a0 = *(const float4*)(xA + kb);
        float4 a1 = *(const float4*)(xA + kb + 4);
        float4 c0 = *(const float4*)(xB + kb);
        float4 c1 = *(const float4*)(xB + kb + 4);
        short8 bF[4];
        #pragma unroll
        for (int nt = 0; nt < 4; ++nt)
            bF[nt] = *(const short8*)(bp + (size_t)nt * 16 * F_IN + kb);
        short8 aF0 = cvt_bf16x8(a0, a1);
        short8 aF1 = cvt_bf16x8(c0, c1);
        #pragma unroll
        for (int nt = 0; nt < 4; ++nt) {
            acc[0][nt] = __builtin_amdgcn_mfma_f32_16x16x32_bf16(aF0, bF[nt], acc[0][nt], 0, 0, 0);
            acc[1][nt] = __builtin_amdgcn_mfma_f32_16x16x32_bf16(aF1, bF[nt], acc[1][nt], 0, 0, 0);
        }
    }

    #pragma unroll
    for (int mt = 0; mt < 2; ++mt) {
        #pragma unroll
        for (int j = 0; j < 4; ++j) {
            const int n = n0 + mt * 16 + kg * 4 + j;
            float sv[4], dv[4];
            #pragma unroll
            for (int nt = 0; nt < 4; ++nt) {
                float v = acc[mt][nt][j];
                sv[nt] = v * a_s[nt];
                dv[nt] = v * a_d[nt];
            }
            #pragma unroll
            for (int m = 1; m < 8; m <<= 1) {
                #pragma unroll
                for (int nt = 0; nt < 4; ++nt) {
                    sv[nt] += __shfl_xor(sv[nt], m);
                    dv[nt] += __shfl_xor(dv[nt], m);
                }
            }
            if (n < N) {
                #pragma unroll
                for (int nt = 0; nt < 4; ++nt)
                    h1b[(size_t)n * C1 + nt * 16 + lo] = f2bf(acc[mt][nt][j]);
                if ((lane & 7) == 0) {
                    const int h0 = (lane >> 3) & 1;
                    #pragma unroll
                    for (int nt = 0; nt < 4; ++nt) {
                        as1[n * H1 + h0 + nt * 2] = sv[nt];
                        ad1[n * H1 + h0 + nt * 2] = dv[nt];
                    }
                }
            }
        }
    }
}

// ---------------------------------------------------------------------------
// fusedA: blocks [0,NBLK) = bhist; rest = gemm1 chunk [g1_beg, ...).
// ---------------------------------------------------------------------------
__global__ __launch_bounds__(256) void fusedA_kernel(
    const int* __restrict__ ei, int* __restrict__ blockhist,
    int E, int nbkt, int chunk,
    const float* __restrict__ x, const unsigned short* __restrict__ Bt1,
    const float* __restrict__ a_src, const float* __restrict__ a_dst,
    unsigned short* __restrict__ h1b, float* __restrict__ as1,
    float* __restrict__ ad1, int N, int g1_beg)
{
    __shared__ int lh[NBKT_MAX];
    const int blk = blockIdx.x;
    const int tid = threadIdx.x;
    if (blk < NBLK) {
        const int b = blk;
        for (int i = tid; i < nbkt; i += 256) lh[i] = 0;
        __syncthreads();
        const int beg = b * chunk;
        const int end = min(E, beg + chunk);
        for (int e = beg + tid; e < end; e += 256)
            atomicAdd(&lh[ei[E + e] >> BKT_SH], 1);
        __syncthreads();
        for (int k = tid; k < nbkt; k += 256)
            blockhist[k * NBLK + b] = lh[k];
        return;
    }
    gemm1_body(g1_beg + blk - NBLK, tid, x, Bt1, a_src, a_dst, h1b, as1, ad1, N);
}

// ---------------------------------------------------------------------------
// Scans (unchanged).
// ---------------------------------------------------------------------------
__global__ __launch_bounds__(512) void scan1_kernel(
    const int* __restrict__ in, int* __restrict__ excl,
    int* __restrict__ bsum, int M)
{
    __shared__ int sA[512], sB[512];
    const int t = threadIdx.x;
    const int i = blockIdx.x * 512 + t;
    int v = (i < M) ? in[i] : 0;
    sA[t] = v; __syncthreads();
    int* pin = sA; int* pout = sB;
    #pragma unroll
    for (int off = 1; off < 512; off <<= 1) {
        pout[t] = pin[t] + ((t >= off) ? pin[t - off] : 0);
        __syncthreads();
        int* tmp = pin; pin = pout; pout = tmp;
    }
    if (i < M) excl[i] = pin[t] - v;
    if (t == 511) bsum[blockIdx.x] = pin[511];
}

__global__ __launch_bounds__(256) void scan2_kernel(
    int* __restrict__ bsum, int* __restrict__ bsumo, int NB)
{
    __shared__ int sA[256], sB[256];
    const int t = threadIdx.x;
    int v = (t < NB) ? bsum[t] : 0;
    sA[t] = v; __syncthreads();
    int* pin = sA; int* pout = sB;
    #pragma unroll
    for (int off = 1; off < 256; off <<= 1) {
        pout[t] = pin[t] + ((t >= off) ? pin[t - off] : 0);
        __syncthreads();
        int* tmp = pin; pin = pout; pout = tmp;
    }
    if (t < NB) bsumo[t] = pin[t] - v;
}

// ---------------------------------------------------------------------------
// fusedB: blocks [0,NBLK) = bpart; rest = gemm1 chunk.
// ---------------------------------------------------------------------------
__global__ __launch_bounds__(256) void fusedB_kernel(
    const int* __restrict__ ei, const int* __restrict__ boffs,
    const int* __restrict__ bsumo, int* __restrict__ ebuf,
    int E, int nbkt, int chunk,
    const float* __restrict__ x, const unsigned short* __restrict__ Bt1,
    const float* __restrict__ a_src, const float* __restrict__ a_dst,
    unsigned short* __restrict__ h1b, float* __restrict__ as1,
    float* __restrict__ ad1, int N, int g1_beg)
{
    __shared__ int cur[NBKT_MAX];
    const int blk = blockIdx.x;
    const int tid = threadIdx.x;
    if (blk < NBLK) {
        const int b = blk;
        for (int k = tid; k < nbkt; k += 256) {
            const int idx = k * NBLK + b;
            cur[k] = boffs[idx] + bsumo[idx >> 9];
        }
        __syncthreads();
        const int beg = b * chunk;
        const int end = min(E, beg + chunk);
        for (int e = beg + tid; e < end; e += 256) {
            int src = ei[e], dst = ei[E + e];
            int pos = atomicAdd(&cur[dst >> BKT_SH], 1);
            ebuf[pos] = (src << BKT_SH) | (dst & (BKT_W - 1));
        }
        return;
    }
    gemm1_body(g1_beg + blk - NBLK, tid, x, Bt1, a_src, a_dst, h1b, as1, ad1, N);
}

// ---------------------------------------------------------------------------
// fusedC: blocks [0,nbkt) = bsort; rest = gemm1 chunk.
// ---------------------------------------------------------------------------
__global__ __launch_bounds__(256) void fusedC_kernel(
    const int* __restrict__ boffs, const int* __restrict__ bsumo,
    const int* __restrict__ ebuf, int* __restrict__ rowptr,
    int* __restrict__ esrc, int N, int E, int nbkt,
    const float* __restrict__ x, const unsigned short* __restrict__ Bt1,
    const float* __restrict__ a_src, const float* __restrict__ a_dst,
    unsigned short* __restrict__ h1b, float* __restrict__ as1,
    float* __restrict__ ad1, int g1_beg)
{
    __shared__ int hist[BKT_W], scn[BKT_W], cur[BKT_W];
    const int blk = blockIdx.x;
    const int tid = threadIdx.x;
    if (blk < nbkt) {
        const int b = blk;
        const int i0 = b * NBLK;
        const int base = boffs[i0] + bsumo[i0 >> 9];
        int nxt;
        if (b == nbkt - 1) nxt = E;
        else {
            const int i1 = (b + 1) * NBLK;
            nxt = boffs[i1] + bsumo[i1 >> 9];
        }
        const int cnt = nxt - base;

        if (tid < BKT_W) hist[tid] = 0;
        __syncthreads();
        for (int i = tid; i < cnt; i += 256)
            atomicAdd(&hist[ebuf[base + i] & (BKT_W - 1)], 1);
        __syncthreads();
        if (tid < BKT_W) scn[tid] = hist[tid];
        __syncthreads();
        #pragma unroll
        for (int off = 1; off < BKT_W; off <<= 1) {
            int add = 0;
            if (tid < BKT_W && tid >= off) add = scn[tid - off];
            __syncthreads();
            if (tid < BKT_W) scn[tid] += add;
            __syncthreads();
        }
        if (tid < BKT_W) {
            int ex = base + scn[tid] - hist[tid];
            cur[tid] = ex;
            int n0 = b * BKT_W + tid;
            if (n0 < N) rowptr[n0] = ex;
        }
        if (b == 0 && tid == 0) rowptr[N] = E;
        __syncthreads();
        for (int i = tid; i < cnt; i += 256) {
            int p = ebuf[base + i];
            int pos = atomicAdd(&cur[p & (BKT_W - 1)], 1);
            esrc[pos] = (unsigned)p >> BKT_SH;
        }
        return;
    }
    gemm1_body(g1_beg + blk - nbkt, tid, x, Bt1, a_src, a_dst, h1b, as1, ad1, N);
}

// ---------------------------------------------------------------------------
// Layer-1 aggregation + finish (R12 version, unchanged).
// ---------------------------------------------------------------------------
__global__ __launch_bounds__(256) void agg1_kernel(
    const int* __restrict__ rowptr, const int* __restrict__ esrc,
    const unsigned short* __restrict__ h1b, const float* __restrict__ as1,
    const float* __restrict__ ad1, const float* __restrict__ b1,
    unsigned short* __restrict__ h1f, int N)
{
    const int n = blockIdx.x * 4 + (threadIdx.x >> 6);
    if (n >= N) return;
    const int lane = threadIdx.x & 63;
    const int h = lane >> 3;
    const float adh = ad1[n * H1 + h];

    float acc = 0.f, den = 0.f;
    int i = rowptr[n];
    const int end = rowptr[n + 1];
    for (; i + 4 <= end; i += 4) {
        const int s0 = esrc[i], s1 = esrc[i + 1], s2 = esrc[i + 2], s3 = esrc[i + 3];
        const float v0 = bf2f(h1b[(size_t)s0 * C1 + lane]);
        const float v1 = bf2f(h1b[(size_t)s1 * C1 + lane]);
        const float v2 = bf2f(h1b[(size_t)s2 * C1 + lane]);
        const float v3 = bf2f(h1b[(size_t)s3 * C1 + lane]);
        const float a0 = as1[s0 * H1 + h], a1 = as1[s1 * H1 + h];
        const float a2 = as1[s2 * H1 + h], a3 = as1[s3 * H1 + h];
        const float e0 = __expf(leaky02(a0 + adh));
        const float e1 = __expf(leaky02(a1 + adh));
        const float e2 = __expf(leaky02(a2 + adh));
        const float e3 = __expf(leaky02(a3 + adh));
        acc += e0 * v0; acc += e1 * v1; acc += e2 * v2; acc += e3 * v3;
        den += (e0 + e1) + (e2 + e3);
    }
    for (; i < end; ++i) {
        const int src = esrc[i];
        const float v  = bf2f(h1b[(size_t)src * C1 + lane]);
        const float ex = __expf(leaky02(as1[src * H1 + h] + adh));
        acc += ex * v;
        den += ex;
    }
    {   // self loop
        const float ex = __expf(leaky02(as1[n * H1 + h] + adh));
        acc += ex * bf2f(h1b[(size_t)n * C1 + lane]);
        den += ex;
    }
    float v = acc / den + b1[lane];
    v = v > 0.f ? v : __expf(v) - 1.f;   // ELU
    h1f[(size_t)n * C1 + lane] = f2bf(v);
}

// ---------------------------------------------------------------------------
// GEMM2 (MFMA bf16, fused alpha2). R12 version, unchanged.
// ---------------------------------------------------------------------------
__global__ __launch_bounds__(256) void gemm2_kernel(
    const unsigned short* __restrict__ h1f, const unsigned short* __restrict__ Bt2,
    const float* __restrict__ a_src2, const float* __restrict__ a_dst2,
    unsigned short* __restrict__ h2b, float* __restrict__ as2,
    float* __restrict__ ad2, int N)
{
    const int tid  = threadIdx.x;
    const int w    = tid >> 6;
    const int lane = tid & 63;
    const int lo   = lane & 15;
    const int kg   = lane >> 4;
    const int n0   = blockIdx.x * 64 + w * 16;

    const int nA = min(n0 + lo, N - 1);
    const unsigned short* ap = h1f + (size_t)nA * C1 + kg * 8;

    float a_s[3], a_d[3];
    #pragma unroll
    for (int nt = 0; nt < 3; ++nt) {
        const int c = nt * 16 + lo;
        a_s[nt] = (c < C2) ? a_src2[c] : 0.f;
        a_d[nt] = (c < C2) ? a_dst2[c] : 0.f;
    }

    f32x4 acc[3];
    #pragma unroll
    for (int nt = 0; nt < 3; ++nt) acc[nt] = (f32x4){0.f, 0.f, 0.f, 0.f};

    #pragma unroll
    for (int ks = 0; ks < 2; ++ks) {
        short8 aF = *(const short8*)(ap + ks * 32);
        #pragma unroll
        for (int nt = 0; nt < 3; ++nt) {
            short8 bF = *(const short8*)(Bt2 + (nt * 16 + lo) * 64 + ks * 32 + kg * 8);
            acc[nt] = __builtin_amdgcn_mfma_f32_16x16x32_bf16(aF, bF, acc[nt], 0, 0, 0);
        }
    }

    #pragma unroll
    for (int j = 0; j < 4; ++j) {
        const int n = n0 + kg * 4 + j;
        float s = acc[0][j] * a_s[0] + acc[1][j] * a_s[1] + acc[2][j] * a_s[2];
        float d = acc[0][j] * a_d[0] + acc[1][j] * a_d[1] + acc[2][j] * a_d[2];
        #pragma unroll
        for (int m = 1; m < 16; m <<= 1) {
            s += __shfl_xor(s, m);
            d += __shfl_xor(d, m);
        }
        if (n < N) {
            #pragma unroll
            for (int nt = 0; nt < 3; ++nt) {
                const int c = nt * 16 + lo;
                if (c < C2) h2b[(size_t)n * C2 + c] = f2bf(acc[nt][j]);
            }
            if (lo == 0) { as2[n] = s; ad2[n] = d; }
        }
    }
}

// ---------------------------------------------------------------------------
// Layer-2 aggregation + finish + log_softmax (R12 version, unchanged).
// ---------------------------------------------------------------------------
__global__ __launch_bounds__(256) void agg2_kernel(
    const int* __restrict__ rowptr, const int* __restrict__ esrc,
    const unsigned short* __restrict__ h2b, const float* __restrict__ as2,
    const float* __restrict__ ad2, const float* __restrict__ b2,
    float* __restrict__ out, int N)
{
    const int n = blockIdx.x * 4 + (threadIdx.x >> 6);
    if (n >= N) return;
    const int lane = threadIdx.x & 63;
    const float adn = ad2[n];

    float acc = 0.f, den = 0.f;
    int i = rowptr[n];
    const int end = rowptr[n + 1];
    for (; i + 4 <= end; i += 4) {
        const int s0 = esrc[i], s1 = esrc[i + 1], s2 = esrc[i + 2], s3 = esrc[i + 3];
        float v0 = 0.f, v1 = 0.f, v2 = 0.f, v3 = 0.f;
        if (lane < C2) {
            v0 = bf2f(h2b[(size_t)s0 * C2 + lane]);
            v1 = bf2f(h2b[(size_t)s1 * C2 + lane]);
            v2 = bf2f(h2b[(size_t)s2 * C2 + lane]);
            v3 = bf2f(h2b[(size_t)s3 * C2 + lane]);
        }
        const float a0 = as2[s0], a1 = as2[s1], a2 = as2[s2], a3 = as2[s3];
        const float e0 = __expf(leaky02(a0 + adn));
        const float e1 = __expf(leaky02(a1 + adn));
        const float e2 = __expf(leaky02(a2 + adn));
        const float e3 = __expf(leaky02(a3 + adn));
        acc += e0 * v0; acc += e1 * v1; acc += e2 * v2; acc += e3 * v3;
        den += (e0 + e1) + (e2 + e3);
    }
    for (; i < end; ++i) {
        const int src = esrc[i];
        float v = (lane < C2) ? bf2f(h2b[(size_t)src * C2 + lane]) : 0.f;
        const float ex = __expf(leaky02(as2[src] + adn));
        acc += ex * v;
        den += ex;
    }
    {   // self loop
        const float ex = __expf(leaky02(as2[n] + adn));
        if (lane < C2) acc += ex * bf2f(h2b[(size_t)n * C2 + lane]);
        den += ex;
    }
    float v = (lane < C2) ? (acc / den + b2[lane]) : -1e30f;
    float m = v;
    #pragma unroll
    for (int s = 1; s < 64; s <<= 1) m = fmaxf(m, __shfl_xor(m, s));
    float e2x = (lane < C2) ? __expf(v - m) : 0.f;
    #pragma unroll
    for (int s = 1; s < 64; s <<= 1) e2x += __shfl_xor(e2x, s);
    float lse = __logf(e2x);
    if (lane < C2) out[(size_t)n * C2 + lane] = v - m - lse;
}

// ---------------------------------------------------------------------------
extern "C" void kernel_launch(void* const* d_in, const int* in_sizes, int n_in,
                              void* d_out, int out_size, void* d_ws, size_t ws_size,
                              hipStream_t stream)
{
    const float* x    = (const float*)d_in[0];
    const int*   ei   = (const int*)  d_in[1];
    const float* W1   = (const float*)d_in[2];
    const float* as1w = (const float*)d_in[3];
    const float* ad1w = (const float*)d_in[4];
    const float* b1   = (const float*)d_in[5];
    const float* W2   = (const float*)d_in[6];
    const float* as2w = (const float*)d_in[7];
    const float* ad2w = (const float*)d_in[8];
    const float* b2   = (const float*)d_in[9];

    const int N = in_sizes[0] / F_IN;   // 100000
    const int E = in_sizes[1] / 2;      // 1600000
    const int nbkt = (N + BKT_W - 1) >> BKT_SH;        // 782
    const int M    = nbkt * NBLK;                      // 100096
    const int chunk = (E + NBLK - 1) / NBLK;           // 12500
    const int G1   = (N + 127) / 128;                  // 782 gemm1 blocks

    // gemm1 filler split across the three CSR-stage launches
    const int CA = G1 / 4;              // with bhist
    const int CB = (G1 * 3) / 8;        // with bpart
    const int CC = G1 - CA - CB;        // with bsort

    char* base = (char*)d_ws;
    auto carve = [&](size_t bytes) -> void* {
        void* p = (void*)base;
        base += (bytes + 255) & ~(size_t)255;
        return p;
    };
    unsigned short* h1b = (unsigned short*)carve((size_t)N * C1 * 2);
    unsigned short* h1f = (unsigned short*)carve((size_t)N * C1 * 2);  // aliased by ebuf
    float* as1    = (float*)carve((size_t)N * H1 * 4);
    float* ad1    = (float*)carve((size_t)N * H1 * 4);
    unsigned short* h2b = (unsigned short*)carve((size_t)N * C2 * 2);
    float* as2    = (float*)carve((size_t)N * 4);
    float* ad2    = (float*)carve((size_t)N * 4);
    int*   rowptr = (int*)carve((size_t)(N + 1) * 4);
    int*   esrc   = (int*)carve((size_t)E * 4);
    int*   boffs  = (int*)carve((size_t)(M + 1) * 4);
    int*   bsum   = (int*)carve(256 * 4);
    int*   bsumo  = (int*)carve(256 * 4);
    unsigned short* Bt1 = (unsigned short*)carve((size_t)F_IN * C1 * 2);
    unsigned short* Bt2 = (unsigned short*)carve((size_t)C2P * 64 * 2);

    // ebuf aliases h1f: ebuf dead after bsort; h1f first written by agg1 later.
    int* ebuf = (int*)h1f;   // E*4 = 6.4 MB <= N*C1*2 = 12.8 MB

    const int NB = (M + 511) / 512;

    wconv_kernel<<<(F_IN * C1 + C2P * 64 + 255) / 256, 256, 0, stream>>>(W1, W2, Bt1, Bt2);

    fusedA_kernel<<<NBLK + CA, 256, 0, stream>>>(
        ei, boffs, E, nbkt, chunk,
        x, Bt1, as1w, ad1w, h1b, as1, ad1, N, 0);

    scan1_kernel<<<NB, 512, 0, stream>>>(boffs, boffs, bsum, M);
    scan2_kernel<<<1, 256, 0, stream>>>(bsum, bsumo, NB);

    fusedB_kernel<<<NBLK + CB, 256, 0, stream>>>(
        ei, boffs, bsumo, ebuf, E, nbkt, chunk,
        x, Bt1, as1w, ad1w, h1b, as1, ad1, N, CA);

    fusedC_kernel<<<nbkt + CC, 256, 0, stream>>>(
        boffs, bsumo, ebuf, rowptr, esrc, N, E, nbkt,
        x, Bt1, as1w, ad1w, h1b, as1, ad1, CA + CB);

    agg1_kernel<<<(N + 3) / 4, 256, 0, stream>>>(rowptr, esrc, h1b, as1, ad1, b1, h1f, N);
    gemm2_kernel<<<(N + 63) / 64, 256, 0, stream>>>(h1f, Bt2, as2w, ad2w, h2b, as2, ad2, N);
    agg2_kernel<<<(N + 3) / 4, 256, 0, stream>>>(rowptr, esrc, h2b, as2, ad2, b2,
                                                 (float*)d_out, N);
}

// Round 14
// 311.018 us; speedup vs baseline: 1.0316x; 1.0316x over previous
//
#include <hip/hip_runtime.h>

#define F_IN 512
#define H1   8
#define D1   8
#define C1   64   // H1*D1
#define C2   40
#define C2P  48   // padded cols for MFMA gemm2

#define BKT_SH   7
#define BKT_W    128
#define NBKT_MAX 1024
#define NBLK     128

using short8 = __attribute__((ext_vector_type(8))) short;
using f32x4  = __attribute__((ext_vector_type(4))) float;
using bf8v   = __attribute__((ext_vector_type(8))) __bf16;

__device__ __forceinline__ float leaky02(float x) { return x > 0.f ? x : 0.2f * x; }
__device__ __forceinline__ float bf2f(unsigned short u) {
    return __builtin_bit_cast(float, ((unsigned)u) << 16);
}
__device__ __forceinline__ unsigned short f2bf(float v) {
    return __builtin_bit_cast(unsigned short, (__bf16)v);
}
__device__ __forceinline__ short8 cvt_bf16x8(float4 a, float4 b) {
    bf8v r;
    r[0] = (__bf16)a.x; r[1] = (__bf16)a.y; r[2] = (__bf16)a.z; r[3] = (__bf16)a.w;
    r[4] = (__bf16)b.x; r[5] = (__bf16)b.y; r[6] = (__bf16)b.z; r[7] = (__bf16)b.w;
    return __builtin_bit_cast(short8, r);
}

// ---------------------------------------------------------------------------
// One-time weight transpose+cast: Bt1 (64x512), Bt2 (48x64, cols>=40 zero).
// ---------------------------------------------------------------------------
__global__ __launch_bounds__(256) void wconv_kernel(
    const float* __restrict__ W1, const float* __restrict__ W2,
    unsigned short* __restrict__ Bt1, unsigned short* __restrict__ Bt2)
{
    int idx = blockIdx.x * 256 + threadIdx.x;
    if (idx < F_IN * C1) {
        int k = idx >> 6, c = idx & 63;
        Bt1[(size_t)c * F_IN + k] = f2bf(W1[idx]);
    } else if (idx < F_IN * C1 + C2P * 64) {
        int j = idx - F_IN * C1;
        int c = j >> 6, k = j & 63;
        float v = (c < C2) ? W2[k * C2 + c] : 0.f;
        Bt2[c * 64 + k] = f2bf(v);
    }
}

// ---------------------------------------------------------------------------
// fused1: blocks [0,G1) = GEMM1 (MFMA bf16, fused alpha1); blocks [G1,G1+NBLK)
// = bhist. Independent work sharing one launch slot (bhist hides under gemm1).
// ---------------------------------------------------------------------------
__global__ __launch_bounds__(256) void fused1_kernel(
    const float* __restrict__ x, const unsigned short* __restrict__ Bt1,
    const float* __restrict__ a_src, const float* __restrict__ a_dst,
    unsigned short* __restrict__ h1b, float* __restrict__ as1,
    float* __restrict__ ad1, int N,
    const int* __restrict__ ei, int* __restrict__ blockhist,
    int E, int nbkt, int chunk, int G1)
{
    __shared__ int lh[NBKT_MAX];
    const int blk = blockIdx.x;
    const int tid = threadIdx.x;

    if (blk >= G1) {
        // ---- bhist path ----
        const int b = blk - G1;
        for (int i = tid; i < nbkt; i += 256) lh[i] = 0;
        __syncthreads();
        const int beg = b * chunk;
        const int end = min(E, beg + chunk);
        for (int e = beg + tid; e < end; e += 256)
            atomicAdd(&lh[ei[E + e] >> BKT_SH], 1);
        __syncthreads();
        for (int k = tid; k < nbkt; k += 256)
            blockhist[k * NBLK + b] = lh[k];
        return;
    }

    // ---- gemm1 path ----
    const int w    = tid >> 6;
    const int lane = tid & 63;
    const int lo   = lane & 15;
    const int kg   = lane >> 4;
    const int n0   = blk * 128 + w * 32;

    const int nA = min(n0 + lo, N - 1);
    const int nB = min(n0 + 16 + lo, N - 1);
    const float* xA = x + (size_t)nA * F_IN + kg * 8;
    const float* xB = x + (size_t)nB * F_IN + kg * 8;
    const unsigned short* bp = Bt1 + (size_t)lo * F_IN + kg * 8;

    float a_s[4], a_d[4];
    #pragma unroll
    for (int nt = 0; nt < 4; ++nt) {
        a_s[nt] = a_src[nt * 16 + lo];
        a_d[nt] = a_dst[nt * 16 + lo];
    }

    f32x4 acc[2][4];
    #pragma unroll
    for (int mt = 0; mt < 2; ++mt)
        #pragma unroll
        for (int nt = 0; nt < 4; ++nt)
            acc[mt][nt] = (f32x4){0.f, 0.f, 0.f, 0.f};

    #pragma unroll 4
    for (int s = 0; s < 16; ++s) {
        const int kb = s * 32;
        float4 a0 = *(const float4*)(xA + kb);
        float4 a1 = *(const float4*)(xA + kb + 4);
        float4 c0 = *(const float4*)(xB + kb);
        float4 c1 = *(const float4*)(xB + kb + 4);
        short8 bF[4];
        #pragma unroll
        for (int nt = 0; nt < 4; ++nt)
            bF[nt] = *(const short8*)(bp + (size_t)nt * 16 * F_IN + kb);
        short8 aF0 = cvt_bf16x8(a0, a1);
        short8 aF1 = cvt_bf16x8(c0, c1);
        #pragma unroll
        for (int nt = 0; nt < 4; ++nt) {
            acc[0][nt] = __builtin_amdgcn_mfma_f32_16x16x32_bf16(aF0, bF[nt], acc[0][nt], 0, 0, 0);
            acc[1][nt] = __builtin_amdgcn_mfma_f32_16x16x32_bf16(aF1, bF[nt], acc[1][nt], 0, 0, 0);
        }
    }

    #pragma unroll
    for (int mt = 0; mt < 2; ++mt) {
        #pragma unroll
        for (int j = 0; j < 4; ++j) {
            const int n = n0 + mt * 16 + kg * 4 + j;
            float sv[4], dv[4];
            #pragma unroll
            for (int nt = 0; nt < 4; ++nt) {
                float v = acc[mt][nt][j];
                sv[nt] = v * a_s[nt];
                dv[nt] = v * a_d[nt];
            }
            #pragma unroll
            for (int m = 1; m < 8; m <<= 1) {
                #pragma unroll
                for (int nt = 0; nt < 4; ++nt) {
                    sv[nt] += __shfl_xor(sv[nt], m);
                    dv[nt] += __shfl_xor(dv[nt], m);
                }
            }
            if (n < N) {
                #pragma unroll
                for (int nt = 0; nt < 4; ++nt)
                    h1b[(size_t)n * C1 + nt * 16 + lo] = f2bf(acc[mt][nt][j]);
                if ((lane & 7) == 0) {
                    const int h0 = (lane >> 3) & 1;
                    #pragma unroll
                    for (int nt = 0; nt < 4; ++nt) {
                        as1[n * H1 + h0 + nt * 2] = sv[nt];
                        ad1[n * H1 + h0 + nt * 2] = dv[nt];
                    }
                }
            }
        }
    }
}

// ---------------------------------------------------------------------------
// Scans + radix partition.
// ---------------------------------------------------------------------------
__global__ __launch_bounds__(512) void scan1_kernel(
    const int* __restrict__ in, int* __restrict__ excl,
    int* __restrict__ bsum, int M)
{
    __shared__ int sA[512], sB[512];
    const int t = threadIdx.x;
    const int i = blockIdx.x * 512 + t;
    int v = (i < M) ? in[i] : 0;
    sA[t] = v; __syncthreads();
    int* pin = sA; int* pout = sB;
    #pragma unroll
    for (int off = 1; off < 512; off <<= 1) {
        pout[t] = pin[t] + ((t >= off) ? pin[t - off] : 0);
        __syncthreads();
        int* tmp = pin; pin = pout; pout = tmp;
    }
    if (i < M) excl[i] = pin[t] - v;
    if (t == 511) bsum[blockIdx.x] = pin[511];
}

__global__ __launch_bounds__(256) void scan2_kernel(
    int* __restrict__ bsum, int* __restrict__ bsumo, int NB)
{
    __shared__ int sA[256], sB[256];
    const int t = threadIdx.x;
    int v = (t < NB) ? bsum[t] : 0;
    sA[t] = v; __syncthreads();
    int* pin = sA; int* pout = sB;
    #pragma unroll
    for (int off = 1; off < 256; off <<= 1) {
        pout[t] = pin[t] + ((t >= off) ? pin[t - off] : 0);
        __syncthreads();
        int* tmp = pin; pin = pout; pout = tmp;
    }
    if (t < NB) bsumo[t] = pin[t] - v;
}

__global__ __launch_bounds__(256) void bpart_kernel(
    const int* __restrict__ ei, const int* __restrict__ boffs,
    const int* __restrict__ bsumo, int* __restrict__ ebuf,
    int E, int nbkt, int chunk)
{
    __shared__ int cur[NBKT_MAX];
    const int b = blockIdx.x;
    for (int k = threadIdx.x; k < nbkt; k += 256) {
        const int idx = k * NBLK + b;
        cur[k] = boffs[idx] + bsumo[idx >> 9];
    }
    __syncthreads();
    const int beg = b * chunk;
    const int end = min(E, beg + chunk);
    for (int e = beg + threadIdx.x; e < end; e += 256) {
        int src = ei[e], dst = ei[E + e];
        int pos = atomicAdd(&cur[dst >> BKT_SH], 1);
        ebuf[pos] = (src << BKT_SH) | (dst & (BKT_W - 1));
    }
}

__global__ __launch_bounds__(256) void bsort_kernel(
    const int* __restrict__ boffs, const int* __restrict__ bsumo,
    const int* __restrict__ ebuf, int* __restrict__ rowptr,
    int* __restrict__ esrc, int N, int E, int nbkt)
{
    const int b = blockIdx.x;
    const int tid = threadIdx.x;
    const int i0 = b * NBLK;
    const int base = boffs[i0] + bsumo[i0 >> 9];
    int nxt;
    if (b == nbkt - 1) nxt = E;
    else {
        const int i1 = (b + 1) * NBLK;
        nxt = boffs[i1] + bsumo[i1 >> 9];
    }
    const int cnt = nxt - base;

    __shared__ int hist[BKT_W], scn[BKT_W], cur[BKT_W];
    if (tid < BKT_W) hist[tid] = 0;
    __syncthreads();
    for (int i = tid; i < cnt; i += 256)
        atomicAdd(&hist[ebuf[base + i] & (BKT_W - 1)], 1);
    __syncthreads();
    if (tid < BKT_W) scn[tid] = hist[tid];
    __syncthreads();
    #pragma unroll
    for (int off = 1; off < BKT_W; off <<= 1) {
        int add = 0;
        if (tid < BKT_W && tid >= off) add = scn[tid - off];
        __syncthreads();
        if (tid < BKT_W) scn[tid] += add;
        __syncthreads();
    }
    if (tid < BKT_W) {
        int ex = base + scn[tid] - hist[tid];
        cur[tid] = ex;
        int n0 = b * BKT_W + tid;
        if (n0 < N) rowptr[n0] = ex;
    }
    if (b == 0 && tid == 0) rowptr[N] = E;
    __syncthreads();
    for (int i = tid; i < cnt; i += 256) {
        int p = ebuf[base + i];
        int pos = atomicAdd(&cur[p & (BKT_W - 1)], 1);
        esrc[pos] = (unsigned)p >> BKT_SH;
    }
}

// ---------------------------------------------------------------------------
// Layer-1 aggregation + finish.
// ---------------------------------------------------------------------------
__global__ __launch_bounds__(256) void agg1_kernel(
    const int* __restrict__ rowptr, const int* __restrict__ esrc,
    const unsigned short* __restrict__ h1b, const float* __restrict__ as1,
    const float* __restrict__ ad1, const float* __restrict__ b1,
    unsigned short* __restrict__ h1f, int N)
{
    const int n = blockIdx.x * 4 + (threadIdx.x >> 6);
    if (n >= N) return;
    const int lane = threadIdx.x & 63;
    const int h = lane >> 3;
    const float adh = ad1[n * H1 + h];

    float acc = 0.f, den = 0.f;
    int i = rowptr[n];
    const int end = rowptr[n + 1];
    for (; i + 4 <= end; i += 4) {
        const int s0 = esrc[i], s1 = esrc[i + 1], s2 = esrc[i + 2], s3 = esrc[i + 3];
        const float v0 = bf2f(h1b[(size_t)s0 * C1 + lane]);
        const float v1 = bf2f(h1b[(size_t)s1 * C1 + lane]);
        const float v2 = bf2f(h1b[(size_t)s2 * C1 + lane]);
        const float v3 = bf2f(h1b[(size_t)s3 * C1 + lane]);
        const float a0 = as1[s0 * H1 + h], a1 = as1[s1 * H1 + h];
        const float a2 = as1[s2 * H1 + h], a3 = as1[s3 * H1 + h];
        const float e0 = __expf(leaky02(a0 + adh));
        const float e1 = __expf(leaky02(a1 + adh));
        const float e2 = __expf(leaky02(a2 + adh));
        const float e3 = __expf(leaky02(a3 + adh));
        acc += e0 * v0; acc += e1 * v1; acc += e2 * v2; acc += e3 * v3;
        den += (e0 + e1) + (e2 + e3);
    }
    for (; i < end; ++i) {
        const int src = esrc[i];
        const float v  = bf2f(h1b[(size_t)src * C1 + lane]);
        const float ex = __expf(leaky02(as1[src * H1 + h] + adh));
        acc += ex * v;
        den += ex;
    }
    {   // self loop
        const float ex = __expf(leaky02(as1[n * H1 + h] + adh));
        acc += ex * bf2f(h1b[(size_t)n * C1 + lane]);
        den += ex;
    }
    float v = acc / den + b1[lane];
    v = v > 0.f ? v : __expf(v) - 1.f;   // ELU
    h1f[(size_t)n * C1 + lane] = f2bf(v);
}

// ---------------------------------------------------------------------------
// GEMM2 (MFMA bf16, fused alpha2).
// ---------------------------------------------------------------------------
__global__ __launch_bounds__(256) void gemm2_kernel(
    const unsigned short* __restrict__ h1f, const unsigned short* __restrict__ Bt2,
    const float* __restrict__ a_src2, const float* __restrict__ a_dst2,
    unsigned short* __restrict__ h2b, float* __restrict__ as2,
    float* __restrict__ ad2, int N)
{
    const int tid  = threadIdx.x;
    const int w    = tid >> 6;
    const int lane = tid & 63;
    const int lo   = lane & 15;
    const int kg   = lane >> 4;
    const int n0   = blockIdx.x * 64 + w * 16;

    const int nA = min(n0 + lo, N - 1);
    const unsigned short* ap = h1f + (size_t)nA * C1 + kg * 8;

    float a_s[3], a_d[3];
    #pragma unroll
    for (int nt = 0; nt < 3; ++nt) {
        const int c = nt * 16 + lo;
        a_s[nt] = (c < C2) ? a_src2[c] : 0.f;
        a_d[nt] = (c < C2) ? a_dst2[c] : 0.f;
    }

    f32x4 acc[3];
    #pragma unroll
    for (int nt = 0; nt < 3; ++nt) acc[nt] = (f32x4){0.f, 0.f, 0.f, 0.f};

    #pragma unroll
    for (int ks = 0; ks < 2; ++ks) {
        short8 aF = *(const short8*)(ap + ks * 32);
        #pragma unroll
        for (int nt = 0; nt < 3; ++nt) {
            short8 bF = *(const short8*)(Bt2 + (nt * 16 + lo) * 64 + ks * 32 + kg * 8);
            acc[nt] = __builtin_amdgcn_mfma_f32_16x16x32_bf16(aF, bF, acc[nt], 0, 0, 0);
        }
    }

    #pragma unroll
    for (int j = 0; j < 4; ++j) {
        const int n = n0 + kg * 4 + j;
        float s = acc[0][j] * a_s[0] + acc[1][j] * a_s[1] + acc[2][j] * a_s[2];
        float d = acc[0][j] * a_d[0] + acc[1][j] * a_d[1] + acc[2][j] * a_d[2];
        #pragma unroll
        for (int m = 1; m < 16; m <<= 1) {
            s += __shfl_xor(s, m);
            d += __shfl_xor(d, m);
        }
        if (n < N) {
            #pragma unroll
            for (int nt = 0; nt < 3; ++nt) {
                const int c = nt * 16 + lo;
                if (c < C2) h2b[(size_t)n * C2 + c] = f2bf(acc[nt][j]);
            }
            if (lo == 0) { as2[n] = s; ad2[n] = d; }
        }
    }
}

// ---------------------------------------------------------------------------
// Layer-2 aggregation + finish + log_softmax.
// ---------------------------------------------------------------------------
__global__ __launch_bounds__(256) void agg2_kernel(
    const int* __restrict__ rowptr, const int* __restrict__ esrc,
    const unsigned short* __restrict__ h2b, const float* __restrict__ as2,
    const float* __restrict__ ad2, const float* __restrict__ b2,
    float* __restrict__ out, int N)
{
    const int n = blockIdx.x * 4 + (threadIdx.x >> 6);
    if (n >= N) return;
    const int lane = threadIdx.x & 63;
    const float adn = ad2[n];

    float acc = 0.f, den = 0.f;
    int i = rowptr[n];
    const int end = rowptr[n + 1];
    for (; i + 4 <= end; i += 4) {
        const int s0 = esrc[i], s1 = esrc[i + 1], s2 = esrc[i + 2], s3 = esrc[i + 3];
        float v0 = 0.f, v1 = 0.f, v2 = 0.f, v3 = 0.f;
        if (lane < C2) {
            v0 = bf2f(h2b[(size_t)s0 * C2 + lane]);
            v1 = bf2f(h2b[(size_t)s1 * C2 + lane]);
            v2 = bf2f(h2b[(size_t)s2 * C2 + lane]);
            v3 = bf2f(h2b[(size_t)s3 * C2 + lane]);
        }
        const float a0 = as2[s0], a1 = as2[s1], a2 = as2[s2], a3 = as2[s3];
        const float e0 = __expf(leaky02(a0 + adn));
        const float e1 = __expf(leaky02(a1 + adn));
        const float e2 = __expf(leaky02(a2 + adn));
        const float e3 = __expf(leaky02(a3 + adn));
        acc += e0 * v0; acc += e1 * v1; acc += e2 * v2; acc += e3 * v3;
        den += (e0 + e1) + (e2 + e3);
    }
    for (; i < end; ++i) {
        const int src = esrc[i];
        float v = (lane < C2) ? bf2f(h2b[(size_t)src * C2 + lane]) : 0.f;
        const float ex = __expf(leaky02(as2[src] + adn));
        acc += ex * v;
        den += ex;
    }
    {   // self loop
        const float ex = __expf(leaky02(as2[n] + adn));
        if (lane < C2) acc += ex * bf2f(h2b[(size_t)n * C2 + lane]);
        den += ex;
    }
    float v = (lane < C2) ? (acc / den + b2[lane]) : -1e30f;
    float m = v;
    #pragma unroll
    for (int s = 1; s < 64; s <<= 1) m = fmaxf(m, __shfl_xor(m, s));
    float e2x = (lane < C2) ? __expf(v - m) : 0.f;
    #pragma unroll
    for (int s = 1; s < 64; s <<= 1) e2x += __shfl_xor(e2x, s);
    float lse = __logf(e2x);
    if (lane < C2) out[(size_t)n * C2 + lane] = v - m - lse;
}

// ---------------------------------------------------------------------------
extern "C" void kernel_launch(void* const* d_in, const int* in_sizes, int n_in,
                              void* d_out, int out_size, void* d_ws, size_t ws_size,
                              hipStream_t stream)
{
    const float* x    = (const float*)d_in[0];
    const int*   ei   = (const int*)  d_in[1];
    const float* W1   = (const float*)d_in[2];
    const float* as1w = (const float*)d_in[3];
    const float* ad1w = (const float*)d_in[4];
    const float* b1   = (const float*)d_in[5];
    const float* W2   = (const float*)d_in[6];
    const float* as2w = (const float*)d_in[7];
    const float* ad2w = (const float*)d_in[8];
    const float* b2   = (const float*)d_in[9];

    const int N = in_sizes[0] / F_IN;   // 100000
    const int E = in_sizes[1] / 2;      // 1600000
    const int nbkt = (N + BKT_W - 1) >> BKT_SH;        // 782
    const int M    = nbkt * NBLK;                      // 100096
    const int chunk = (E + NBLK - 1) / NBLK;           // 12500
    const int G1   = (N + 127) / 128;                  // 782 gemm1 blocks

    char* base = (char*)d_ws;
    auto carve = [&](size_t bytes) -> void* {
        void* p = (void*)base;
        base += (bytes + 255) & ~(size_t)255;
        return p;
    };
    unsigned short* h1b = (unsigned short*)carve((size_t)N * C1 * 2);
    unsigned short* h1f = (unsigned short*)carve((size_t)N * C1 * 2);  // aliased by ebuf
    float* as1    = (float*)carve((size_t)N * H1 * 4);
    float* ad1    = (float*)carve((size_t)N * H1 * 4);
    unsigned short* h2b = (unsigned short*)carve((size_t)N * C2 * 2);
    float* as2    = (float*)carve((size_t)N * 4);
    float* ad2    = (float*)carve((size_t)N * 4);
    int*   rowptr = (int*)carve((size_t)(N + 1) * 4);
    int*   esrc   = (int*)carve((size_t)E * 4);
    int*   boffs  = (int*)carve((size_t)(M + 1) * 4);
    int*   bsum   = (int*)carve(256 * 4);
    int*   bsumo  = (int*)carve(256 * 4);
    unsigned short* Bt1 = (unsigned short*)carve((size_t)F_IN * C1 * 2);
    unsigned short* Bt2 = (unsigned short*)carve((size_t)C2P * 64 * 2);

    // ebuf aliases h1f: ebuf dead after bsort; h1f first written by agg1 later.
    int* ebuf = (int*)h1f;   // E*4 = 6.4 MB <= N*C1*2 = 12.8 MB

    const int NB = (M + 511) / 512;

    wconv_kernel<<<(F_IN * C1 + C2P * 64 + 255) / 256, 256, 0, stream>>>(W1, W2, Bt1, Bt2);

    fused1_kernel<<<G1 + NBLK, 256, 0, stream>>>(
        x, Bt1, as1w, ad1w, h1b, as1, ad1, N, ei, boffs, E, nbkt, chunk, G1);

    scan1_kernel<<<NB, 512, 0, stream>>>(boffs, boffs, bsum, M);
    scan2_kernel<<<1, 256, 0, stream>>>(bsum, bsumo, NB);
    bpart_kernel<<<NBLK, 256, 0, stream>>>(ei, boffs, bsumo, ebuf, E, nbkt, chunk);
    bsort_kernel<<<nbkt, 256, 0, stream>>>(boffs, bsumo, ebuf, rowptr, esrc, N, E, nbkt);

    agg1_kernel<<<(N + 3) / 4, 256, 0, stream>>>(rowptr, esrc, h1b, as1, ad1, b1, h1f, N);
    gemm2_kernel<<<(N + 63) / 64, 256, 0, stream>>>(h1f, Bt2, as2w, ad2w, h2b, as2, ad2, N);
    agg2_kernel<<<(N + 3) / 4, 256, 0, stream>>>(rowptr, esrc, h2b, as2, ad2, b2,
                                                 (float*)d_out, N);
}